// Round 8
// baseline (520.565 us; speedup 1.0000x reference)
//
#include <hip/hip_runtime.h>
#include <stdint.h>

typedef _Float16 f16;
typedef _Float16 half8 __attribute__((ext_vector_type(8)));
typedef _Float16 half4 __attribute__((ext_vector_type(4)));
typedef float floatx16 __attribute__((ext_vector_type(16)));

#define NIMG 3072

// ws byte offsets (all 16B-aligned)
#define WS_W0T   0           // f16 [5ky][2ch][2hf][32co][8j]            = 5,120
#define WS_W1T   10240       // f16 [25tap][2ch][2hf][32co][8j]          = 25,600
#define WS_W2T   61440       // f16 [16tap][2ch][2ct][2hf][32co][8j]     = 32,768
#define WS_W3T   126976      // f16 [36c][2ct][2hf][32col][8j]           = 36,864
#define WS_FC1T  200704      // f16 [6l][16c][4nt][2hf][32][8]           = 196,608
#define WS_FC2T  593920      // f16 [6l][8c][2nt][2hf][32][8]            = 49,152
#define WS_FC3T  692224      // f16 [6l][4c][2hf][32][8]                 = 12,288
#define WS_H3F   720896      // f16 3072*1024, NHWC [16pos][64ci]        = 6,291,456

#define Z16 {0.f,0.f,0.f,0.f,0.f,0.f,0.f,0.f,0.f,0.f,0.f,0.f,0.f,0.f,0.f,0.f}

// ---------------- weight transform ----------------
__global__ __launch_bounds__(256) void k_prep(
    const float* __restrict__ w0, const float* __restrict__ w1, const float* __restrict__ w2,
    const float* __restrict__ w3, const float* __restrict__ fc1w, const float* __restrict__ fc2w,
    const float* __restrict__ fc3w,
    f16* __restrict__ w0t, f16* __restrict__ w1t, f16* __restrict__ w2t, f16* __restrict__ w3t,
    f16* __restrict__ fc1t, f16* __restrict__ fc2t, f16* __restrict__ fc3t)
{
  int stride = gridDim.x * blockDim.x;
  int g0 = blockIdx.x * blockDim.x + threadIdx.x;
  for (int i = g0; i < 5120; i += stride) {
    int j = i & 7, co = (i >> 3) & 31, hf = (i >> 8) & 1, ch = (i >> 9) & 1, ky = i >> 10;
    int k = ch * 16 + hf * 8 + j;
    f16 v = (f16)0.f;
    if (k < 20) { int kx = k >> 2, ci = k & 3; v = (f16)w0[((co * 4 + ci) * 5 + ky) * 5 + kx]; }
    w0t[i] = v;
  }
  for (int i = g0; i < 25600; i += stride) {
    int j = i & 7, co = (i >> 3) & 31, hf = (i >> 8) & 1, ch = (i >> 9) & 1, tap = i >> 10;
    int ci = ch * 16 + hf * 8 + j, ky = tap / 5, kx = tap % 5;
    w1t[i] = (f16)w1[((co * 32 + ci) * 5 + ky) * 5 + kx];
  }
  for (int i = g0; i < 32768; i += stride) {
    int j = i & 7, co = (i >> 3) & 31, hf = (i >> 8) & 1, ct = (i >> 9) & 1, ch = (i >> 10) & 1, tap = i >> 11;
    int ci = ch * 16 + hf * 8 + j, cog = ct * 32 + co, ky = tap >> 2, kx = tap & 3;
    w2t[i] = (f16)w2[((cog * 32 + ci) * 4 + ky) * 4 + kx];
  }
  for (int i = g0; i < 36864; i += stride) {
    int j = i & 7, col = (i >> 3) & 31, hf = (i >> 8) & 1, ct = (i >> 9) & 1, c = i >> 10;
    int k = c * 16 + hf * 8 + j, tap = k >> 6, ci = k & 63, co = ct * 32 + col;
    int ky = tap / 3, kx = tap % 3;
    w3t[i] = (f16)w3[((co * 64 + ci) * 3 + ky) * 3 + kx];
  }
  for (int i = g0; i < 196608; i += stride) {
    int j = i & 7, col = (i >> 3) & 31, hf = (i >> 8) & 1, nt = (i >> 9) & 3, c = (i >> 11) & 15, l = i >> 15;
    int k = c * 16 + hf * 8 + j, o = nt * 32 + col;
    fc1t[i] = (f16)fc1w[(l * 256 + k) * 128 + o];
  }
  for (int i = g0; i < 49152; i += stride) {
    int j = i & 7, col = (i >> 3) & 31, hf = (i >> 8) & 1, nt = (i >> 9) & 1, c = (i >> 10) & 7, l = i >> 13;
    int k = c * 16 + hf * 8 + j, o = nt * 32 + col;
    fc2t[i] = (f16)fc2w[(l * 128 + k) * 64 + o];
  }
  for (int i = g0; i < 12288; i += stride) {
    int j = i & 7, col = (i >> 3) & 31, hf = (i >> 8) & 1, c = (i >> 9) & 3, l = i >> 11;
    int k = c * 16 + hf * 8 + j;
    f16 v = (f16)0.f;
    if (col < 4) v = (f16)fc3w[(l * 64 + k) * 4 + col];
    fc3t[i] = v;
  }
}

// ---- fused conv0+pool + conv1+pool + conv2+pool (MFMA f16), one image/block ----
// LDS cut to 53,728 B (3 blocks/CU): x staged in two row-slabs, s_h1 ci-stride 36.
__global__ __launch_bounds__(512) void k_conv012(
    const float* __restrict__ x,
    const f16* __restrict__ w0t, const float* __restrict__ b0, const float* __restrict__ a0p,
    const f16* __restrict__ w1t, const float* __restrict__ b1, const float* __restrict__ a1p,
    const f16* __restrict__ w2t, const float* __restrict__ b2, const float* __restrict__ a2p,
    f16* __restrict__ h3f)
{
  __shared__ __align__(16) uint32_t smem_u[13432];   // 53,728 B
  f16* sh   = (f16*)smem_u;
  f16* s_xh = sh;            // [28][56][4] = 6,272 f16 (x slab, two phases)
  f16* s_h1 = sh + 6272;     // [22][26][36] = 20,592 f16 (NHWC +1 shift, ci-stride 36)
  f16* s_h2 = sh;            // [12][12][40] = 5,760 f16 (aliases s_xh after conv0)

  const int n = blockIdx.x, tid = threadIdx.x;
  const int wv = tid >> 6, l = tid & 63;
  const int hf = l >> 5, m = l & 31, dr = m >> 3, dc = m & 7, col = m;
  const float a0 = a0p[0], a1 = a1p[0];
  const float b0c = b0[col], b1c = b1[col];
  const half8* w0t8 = (const half8*)w0t;
  const half8* w1t8 = (const half8*)w1t;
  const half8* w2t8 = (const half8*)w2t;

  {
    uint4 zz = {0u, 0u, 0u, 0u};
    uint4* z = (uint4*)smem_u;
    for (int i = tid; i < 3358; i += 512) z[i] = zz;
  }
  __syncthreads();

  const float* xin = x + n * 8100;
  // stage phase A: x rows 0..26 -> buffer rows 1..27 (row 0 = zero pad)
  for (int i = tid; i < 4860; i += 512) {
    int ci = i / 1215, rem = i - ci * 1215;
    int yy = rem / 45, xx = rem - yy * 45;
    s_xh[((yy + 1) * 56 + (xx + 1)) * 4 + ci] = (f16)xin[ci * 2025 + rem];
  }
  __syncthreads();

  // ---- conv0 weights resident ----
  half8 B0[5][2];
  #pragma unroll
  for (int ky = 0; ky < 5; ++ky)
    #pragma unroll
    for (int ch = 0; ch < 2; ++ch)
      B0[ky][ch] = w0t8[(ky * 2 + ch) * 64 + hf * 32 + col];

  // ---- conv0 phase A: tiles 0..35 (r0 = 0..20), buffer row = x row + 1 ----
  for (int t = wv; t < 36; t += 8) {
    int r0 = (t / 6) * 4, cb = (t % 6) * 8;
    const f16* pA = s_xh + ((r0 + dr) * 56 + cb + dc + 2 * hf) * 4;
    floatx16 acc = Z16;
    #pragma unroll
    for (int ky = 0; ky < 5; ++ky) {
      const f16* p = pA + ky * 224;
      half4 l0  = *(const half4*)(p);
      half4 h0  = *(const half4*)(p + 4);
      half4 l1  = *(const half4*)(p + 16);
      half4 h1v = *(const half4*)(p + 20);
      half8 a0v = __builtin_shufflevector(l0, h0, 0,1,2,3,4,5,6,7);
      half8 a1v = __builtin_shufflevector(l1, h1v, 0,1,2,3,4,5,6,7);
      acc = __builtin_amdgcn_mfma_f32_32x32x16_f16(a0v, B0[ky][0], acc, 0, 0, 0);
      acc = __builtin_amdgcn_mfma_f32_32x32x16_f16(a1v, B0[ky][1], acc, 0, 0, 0);
    }
    #pragma unroll
    for (int pp = 0; pp < 2; ++pp)
      #pragma unroll
      for (int c2 = 0; c2 < 2; ++c2) {
        float v = fmaxf(fmaxf(acc[8*pp + 2*c2], acc[8*pp + 2*c2 + 1]),
                        fmaxf(acc[8*pp + 4 + 2*c2], acc[8*pp + 4 + 2*c2 + 1]));
        v += b0c; v = (v >= 0.f) ? v : a0 * v;
        int pr = (r0 >> 1) + pp, pc = (cb >> 1) + 2 * hf + c2;
        if (pc < 21) s_h1[((pr + 1) * 26 + (pc + 1)) * 36 + col] = (f16)v;
      }
  }
  __syncthreads();   // phase A reads done

  // stage phase B: x rows 23..44 -> buffer rows 0..21 (col pads persist from zero pass)
  for (int i = tid; i < 3960; i += 512) {
    int ci = i / 990, rem = i - ci * 990;
    int yy = rem / 45, xx = rem - yy * 45;
    s_xh[(yy * 56 + (xx + 1)) * 4 + ci] = (f16)xin[ci * 2025 + (yy + 23) * 45 + xx];
  }
  __syncthreads();

  // ---- conv0 phase B: tiles 36..65 (r0 = 24,28,32,36,38), buffer row = x row - 23 ----
  for (int t = 36 + wv; t < 66; t += 8) {
    int q = (t - 36) / 6, rr = (t - 36) - q * 6;
    int r0 = min(24 + q * 4, 38), cb = rr * 8;
    const f16* pA = s_xh + ((r0 - 24 + dr) * 56 + cb + dc + 2 * hf) * 4;
    floatx16 acc = Z16;
    #pragma unroll
    for (int ky = 0; ky < 5; ++ky) {
      const f16* p = pA + ky * 224;
      half4 l0  = *(const half4*)(p);
      half4 h0  = *(const half4*)(p + 4);
      half4 l1  = *(const half4*)(p + 16);
      half4 h1v = *(const half4*)(p + 20);
      half8 a0v = __builtin_shufflevector(l0, h0, 0,1,2,3,4,5,6,7);
      half8 a1v = __builtin_shufflevector(l1, h1v, 0,1,2,3,4,5,6,7);
      acc = __builtin_amdgcn_mfma_f32_32x32x16_f16(a0v, B0[ky][0], acc, 0, 0, 0);
      acc = __builtin_amdgcn_mfma_f32_32x32x16_f16(a1v, B0[ky][1], acc, 0, 0, 0);
    }
    #pragma unroll
    for (int pp = 0; pp < 2; ++pp)
      #pragma unroll
      for (int c2 = 0; c2 < 2; ++c2) {
        float v = fmaxf(fmaxf(acc[8*pp + 2*c2], acc[8*pp + 2*c2 + 1]),
                        fmaxf(acc[8*pp + 4 + 2*c2], acc[8*pp + 4 + 2*c2 + 1]));
        v += b0c; v = (v >= 0.f) ? v : a0 * v;
        int pr = (r0 >> 1) + pp, pc = (cb >> 1) + 2 * hf + c2;
        if (pc < 21) s_h1[((pr + 1) * 26 + (pc + 1)) * 36 + col] = (f16)v;
      }
  }
  __syncthreads();   // s_h1 complete, s_xh dead

  for (int i = tid; i < 2880; i += 512) smem_u[i] = 0u;   // zero s_h2 (pads must be 0)
  __syncthreads();

  // ---- conv1: 25 taps, K=32ci; 15 tiles32, 2 per wave; epilogue -> s_h2 ----
  const int r0lut1[5] = {0, 4, 8, 12, 14};
  const int cclut[3]  = {0, 8, 14};
  int t0 = wv * 2;
  int t1 = t0 + 1; if (t1 > 14) t1 = 14;
  int r0a = r0lut1[t0 / 3], cca = cclut[t0 % 3];
  int r0b = r0lut1[t1 / 3], ccb = cclut[t1 % 3];
  const f16* pAa = s_h1 + ((r0a + dr) * 26 + cca + dc) * 36 + hf * 8;
  const f16* pAb = s_h1 + ((r0b + dr) * 26 + ccb + dc) * 36 + hf * 8;
  floatx16 accA = Z16;
  floatx16 accB = Z16;
  for (int ky = 0; ky < 5; ++ky) {
    const half8* wb = w1t8 + ky * 640 + hf * 32 + col;
    const f16* qa = pAa + ky * 936;
    const f16* qb = pAb + ky * 936;
    #pragma unroll
    for (int kx = 0; kx < 5; ++kx) {
      #pragma unroll
      for (int ch = 0; ch < 2; ++ch) {
        half8 b  = wb[kx * 128 + ch * 64];
        half8 aA = *(const half8*)(qa + kx * 36 + ch * 16);
        half8 aB = *(const half8*)(qb + kx * 36 + ch * 16);
        accA = __builtin_amdgcn_mfma_f32_32x32x16_f16(aA, b, accA, 0, 0, 0);
        accB = __builtin_amdgcn_mfma_f32_32x32x16_f16(aB, b, accB, 0, 0, 0);
      }
    }
  }
  #pragma unroll
  for (int tt = 0; tt < 2; ++tt) {
    const floatx16 acc = tt ? accB : accA;
    int r0 = tt ? r0b : r0a, cc = tt ? ccb : cca;
    #pragma unroll
    for (int pp = 0; pp < 2; ++pp)
      #pragma unroll
      for (int c2 = 0; c2 < 2; ++c2) {
        float v = fmaxf(fmaxf(acc[8*pp + 2*c2], acc[8*pp + 2*c2 + 1]),
                        fmaxf(acc[8*pp + 4 + 2*c2], acc[8*pp + 4 + 2*c2 + 1]));
        v += b1c; v = (v >= 0.f) ? v : a1 * v;
        int pr = (r0 >> 1) + pp, pc = (cc >> 1) + 2 * hf + c2;
        if (pc < 9) s_h2[((pr + 1) * 12 + (pc + 1)) * 40 + col] = (f16)v;
      }
  }
  __syncthreads();   // s_h2 complete

  // ---- conv2: 4 waves (mt x ct), 32 MFMA each; epilogue -> h3f (global f16 NHWC) ----
  if (wv < 4) {
    const int mt = wv >> 1, ct = wv & 1;
    const float a2 = a2p[0];
    const float b2c = b2[ct * 32 + col];
    const f16* pA = s_h2 + ((mt * 4 + dr) * 12 + dc) * 40 + hf * 8;
    floatx16 acc = Z16;
    for (int tap = 0; tap < 16; ++tap) {
      int ky = tap >> 2, kx = tap & 3;
      int aoff = (ky * 12 + kx) * 40;
      #pragma unroll
      for (int ch = 0; ch < 2; ++ch) {
        half8 b  = w2t8[tap * 256 + ch * 128 + ct * 64 + hf * 32 + col];
        half8 av = *(const half8*)(pA + aoff + ch * 16);
        acc = __builtin_amdgcn_mfma_f32_32x32x16_f16(av, b, acc, 0, 0, 0);
      }
    }
    f16* o = h3f + n * 1024;
    #pragma unroll
    for (int pp = 0; pp < 2; ++pp)
      #pragma unroll
      for (int c2 = 0; c2 < 2; ++c2) {
        float v = fmaxf(fmaxf(acc[8*pp + 2*c2], acc[8*pp + 2*c2 + 1]),
                        fmaxf(acc[8*pp + 4 + 2*c2], acc[8*pp + 4 + 2*c2 + 1]));
        v += b2c; v = (v >= 0.f) ? v : a2 * v;
        int pr = mt * 2 + pp, pc = 2 * hf + c2, co = ct * 32 + col;
        o[(pr * 4 + pc) * 64 + co] = (f16)v;
      }
  }
}

// ---------------- fused conv3 + fc1 + fc2 + fc3 (MFMA f16) ----------------
// grid 96: blockIdx -> landmark l = b%6, image tile t = b/6 (32 images, n = (32t+i)*6+l)
__global__ __launch_bounds__(256) void k_tail(
    const f16* __restrict__ h3f,
    const f16* __restrict__ w3t, const float* __restrict__ b3, const float* __restrict__ a3p,
    const f16* __restrict__ fc1t, const float* __restrict__ fc1b, const float* __restrict__ a4,
    const f16* __restrict__ fc2t, const float* __restrict__ fc2b, const float* __restrict__ a5,
    const f16* __restrict__ fc3t, const float* __restrict__ fc3b,
    float* __restrict__ out)
{
  __shared__ __align__(16) f16 s_feat[32 * 264];
  __shared__ __align__(16) f16 s_g1[32 * 136];
  __shared__ __align__(16) f16 s_g2[32 * 72];

  const int lm = blockIdx.x % 6, t = blockIdx.x / 6;
  const int tid = threadIdx.x, wv = tid >> 6, lane = tid & 63;
  const int hf = lane >> 5, col = lane & 31;
  const half8* w3t8  = (const half8*)w3t;
  const half8* fc1t8 = (const half8*)fc1t;
  const half8* fc2t8 = (const half8*)fc2t;
  const half8* fc3t8 = (const half8*)fc3t;

  {
    const int mt = wv;
    const int i_img = mt * 8 + (col >> 2);
    const int pos = col & 3, oy = pos >> 1, ox = pos & 1;
    const int gimg = (t * 32 + i_img) * 6 + lm;
    const f16* Abase = h3f + gimg * 1024 + (oy * 4 + ox) * 64;
    floatx16 acc0 = Z16, acc1 = Z16;
    for (int c = 0; c < 36; ++c) {
      int tap = c >> 2;
      int ky = tap / 3, kx = tap % 3;
      half8 a = *(const half8*)(Abase + (ky * 4 + kx) * 64 + (c & 3) * 16 + hf * 8);
      half8 bb0 = w3t8[((c * 2 + 0) * 2 + hf) * 32 + col];
      half8 bb1 = w3t8[((c * 2 + 1) * 2 + hf) * 32 + col];
      acc0 = __builtin_amdgcn_mfma_f32_32x32x16_f16(a, bb0, acc0, 0, 0, 0);
      acc1 = __builtin_amdgcn_mfma_f32_32x32x16_f16(a, bb1, acc1, 0, 0, 0);
    }
    const float a3 = a3p[0];
    #pragma unroll
    for (int ct = 0; ct < 2; ++ct) {
      const floatx16 acc = ct ? acc1 : acc0;
      const int co = ct * 32 + col;
      const float bb = b3[co];
      #pragma unroll
      for (int q = 0; q < 4; ++q) {
        int ii = mt * 8 + 2 * q + hf;
        half4 w;
        #pragma unroll
        for (int z = 0; z < 4; ++z) {
          float v = acc[q * 4 + z] + bb;
          v = (v >= 0.f) ? v : a3 * v;
          w[z] = (f16)v;
        }
        *(half4*)(s_feat + ii * 264 + co * 4) = w;
      }
    }
  }
  __syncthreads();

  {
    floatx16 g = Z16;
    for (int c = 0; c < 16; ++c) {
      half8 a = *(const half8*)(s_feat + col * 264 + c * 16 + hf * 8);
      half8 b = fc1t8[(((lm * 16 + c) * 4 + wv) * 2 + hf) * 32 + col];
      g = __builtin_amdgcn_mfma_f32_32x32x16_f16(a, b, g, 0, 0, 0);
    }
    const float a4v = a4[lm];
    const float bb = fc1b[lm * 128 + wv * 32 + col];
    #pragma unroll
    for (int reg = 0; reg < 16; ++reg) {
      int r = (reg & 3) + 8 * (reg >> 2) + 4 * hf;
      float v = g[reg] + bb;
      v = (v >= 0.f) ? v : a4v * v;
      s_g1[r * 136 + wv * 32 + col] = (f16)v;
    }
  }
  __syncthreads();

  if (wv < 2) {
    floatx16 g = Z16;
    for (int c = 0; c < 8; ++c) {
      half8 a = *(const half8*)(s_g1 + col * 136 + c * 16 + hf * 8);
      half8 b = fc2t8[(((lm * 8 + c) * 2 + wv) * 2 + hf) * 32 + col];
      g = __builtin_amdgcn_mfma_f32_32x32x16_f16(a, b, g, 0, 0, 0);
    }
    const float a5v = a5[lm];
    const float bb = fc2b[lm * 64 + wv * 32 + col];
    #pragma unroll
    for (int reg = 0; reg < 16; ++reg) {
      int r = (reg & 3) + 8 * (reg >> 2) + 4 * hf;
      float v = g[reg] + bb;
      v = (v >= 0.f) ? v : a5v * v;
      s_g2[r * 72 + wv * 32 + col] = (f16)v;
    }
  }
  __syncthreads();

  if (wv == 0) {
    floatx16 g = Z16;
    for (int c = 0; c < 4; ++c) {
      half8 a = *(const half8*)(s_g2 + col * 72 + c * 16 + hf * 8);
      half8 b = fc3t8[((lm * 4 + c) * 2 + hf) * 32 + col];
      g = __builtin_amdgcn_mfma_f32_32x32x16_f16(a, b, g, 0, 0, 0);
    }
    if (col < 4) {
      const float bb = fc3b[lm * 4 + col];
      #pragma unroll
      for (int reg = 0; reg < 16; ++reg) {
        int r = (reg & 3) + 8 * (reg >> 2) + 4 * hf;
        out[((t * 32 + r) * 6 + lm) * 4 + col] = g[reg] + bb;
      }
    }
  }
}

extern "C" void kernel_launch(void* const* d_in, const int* in_sizes, int n_in,
                              void* d_out, int out_size, void* d_ws, size_t ws_size,
                              hipStream_t stream) {
  const float* x    = (const float*)d_in[0];
  const float* w0   = (const float*)d_in[1];
  const float* b0   = (const float*)d_in[2];
  const float* w1   = (const float*)d_in[3];
  const float* b1   = (const float*)d_in[4];
  const float* w2   = (const float*)d_in[5];
  const float* b2   = (const float*)d_in[6];
  const float* w3   = (const float*)d_in[7];
  const float* b3   = (const float*)d_in[8];
  const float* a0   = (const float*)d_in[9];
  const float* a1   = (const float*)d_in[10];
  const float* a2   = (const float*)d_in[11];
  const float* a3   = (const float*)d_in[12];
  const float* fc1w = (const float*)d_in[13];
  const float* fc1b = (const float*)d_in[14];
  const float* a4   = (const float*)d_in[15];
  const float* fc2w = (const float*)d_in[16];
  const float* fc2b = (const float*)d_in[17];
  const float* a5   = (const float*)d_in[18];
  const float* fc3w = (const float*)d_in[19];
  const float* fc3b = (const float*)d_in[20];
  float* out = (float*)d_out;

  char* ws = (char*)d_ws;
  f16* w0t  = (f16*)(ws + WS_W0T);
  f16* w1t  = (f16*)(ws + WS_W1T);
  f16* w2t  = (f16*)(ws + WS_W2T);
  f16* w3t  = (f16*)(ws + WS_W3T);
  f16* fc1t = (f16*)(ws + WS_FC1T);
  f16* fc2t = (f16*)(ws + WS_FC2T);
  f16* fc3t = (f16*)(ws + WS_FC3T);
  f16* h3f  = (f16*)(ws + WS_H3F);

  k_prep   <<<128, 256, 0, stream>>>(w0, w1, w2, w3, fc1w, fc2w, fc3w,
                                     w0t, w1t, w2t, w3t, fc1t, fc2t, fc3t);
  k_conv012<<<NIMG, 512, 0, stream>>>(x, w0t, b0, a0, w1t, b1, a1, w2t, b2, a2, h3f);
  k_tail   <<<96, 256, 0, stream>>>(h3f, w3t, b3, a3, fc1t, fc1b, a4,
                                    fc2t, fc2b, a5, fc3t, fc3b, out);
}